// Round 1
// baseline (1734.278 us; speedup 1.0000x reference)
//
#include <hip/hip_runtime.h>
#include <hip/hip_bf16.h>

#define NN 50000
#define CC 64
#define GG 3
#define EE 1200000
#define LL 2
#define DD 256
#define HH 256

// ---------------------------------------------------------------------------
// GEMM: C[M,Nc] = act(A[M,K] @ B[K,Nc] + bias), fp32, 64x64 tile, 4x4 micro
// ---------------------------------------------------------------------------
__global__ __launch_bounds__(256) void gemm_kernel(
    const float* __restrict__ A, const float* __restrict__ B,
    const float* __restrict__ bias, float* __restrict__ Cout,
    int M, int Nc, int K, int do_relu)
{
    __shared__ float As[16][68];   // [k][m], pad 68 keeps 16B alignment, odd-ish banks
    __shared__ float Bs[16][64];   // [k][n]
    int tid = threadIdx.x;
    int tx = tid & 15;             // col group (4 cols each)
    int ty = tid >> 4;             // row group (4 rows each)
    int m0 = blockIdx.x * 64;
    int n0 = blockIdx.y * 64;
    float acc[4][4] = {};

    for (int k0 = 0; k0 < K; k0 += 16) {
        {   // A tile: 64 rows x 16 k
            int kk = tid & 15;
            int mm = tid >> 4;     // 0..15
            #pragma unroll
            for (int i = 0; i < 4; i++) {
                int m = m0 + mm + i * 16;
                float v = (m < M) ? A[(size_t)m * K + k0 + kk] : 0.f;
                As[kk][mm + i * 16] = v;
            }
        }
        {   // B tile: 16 k x 64 n
            int nn = tid & 63;
            int kk = tid >> 6;     // 0..3
            #pragma unroll
            for (int i = 0; i < 4; i++) {
                Bs[kk + i * 4][nn] = B[(size_t)(k0 + kk + i * 4) * Nc + n0 + nn];
            }
        }
        __syncthreads();
        #pragma unroll
        for (int kk = 0; kk < 16; kk++) {
            float4 a4 = *(const float4*)&As[kk][ty * 4];
            float4 b4 = *(const float4*)&Bs[kk][tx * 4];
            acc[0][0] += a4.x * b4.x; acc[0][1] += a4.x * b4.y;
            acc[0][2] += a4.x * b4.z; acc[0][3] += a4.x * b4.w;
            acc[1][0] += a4.y * b4.x; acc[1][1] += a4.y * b4.y;
            acc[1][2] += a4.y * b4.z; acc[1][3] += a4.y * b4.w;
            acc[2][0] += a4.z * b4.x; acc[2][1] += a4.z * b4.y;
            acc[2][2] += a4.z * b4.z; acc[2][3] += a4.z * b4.w;
            acc[3][0] += a4.w * b4.x; acc[3][1] += a4.w * b4.y;
            acc[3][2] += a4.w * b4.z; acc[3][3] += a4.w * b4.w;
        }
        __syncthreads();
    }
    #pragma unroll
    for (int i = 0; i < 4; i++) {
        int m = m0 + ty * 4 + i;
        if (m >= M) continue;
        #pragma unroll
        for (int j = 0; j < 4; j++) {
            int n = n0 + tx * 4 + j;
            float v = acc[i][j] + bias[n];
            if (do_relu) v = fmaxf(v, 0.f);
            Cout[(size_t)m * Nc + n] = v;
        }
    }
}

// ---------------------------------------------------------------------------
// CSR build
// ---------------------------------------------------------------------------
__global__ void hist_kernel(const int* __restrict__ dst, int* __restrict__ counts)
{
    int idx = blockIdx.x * blockDim.x + threadIdx.x;
    if (idx >= GG * EE) return;
    int g = idx / EE;
    atomicAdd(&counts[g * NN + dst[idx]], 1);
}

__global__ void scan_kernel(const int* __restrict__ counts, int* __restrict__ row_start)
{
    int g = blockIdx.x;
    const int* cnt = counts + (size_t)g * NN;
    int* rs = row_start + (size_t)g * (NN + 1);
    __shared__ int sdata[256];
    __shared__ int s_running;
    int t = threadIdx.x;
    if (t == 0) s_running = 0;
    __syncthreads();
    for (int base = 0; base < NN; base += 256) {
        int i = base + t;
        int v = (i < NN) ? cnt[i] : 0;
        sdata[t] = v;
        __syncthreads();
        for (int offp = 1; offp < 256; offp <<= 1) {
            int x = (t >= offp) ? sdata[t - offp] : 0;
            __syncthreads();
            sdata[t] += x;
            __syncthreads();
        }
        int incl = sdata[t];
        int run = s_running;
        __syncthreads();
        if (i < NN) rs[i] = run + incl - v;       // exclusive
        if (t == 255) s_running = run + sdata[255];
        __syncthreads();
    }
    if (t == 0) rs[NN] = s_running;
}

__global__ void scatter_kernel(const int* __restrict__ dst, const int* __restrict__ src,
                               const int* __restrict__ row_start, int* __restrict__ fill,
                               int* __restrict__ src_csr, int* __restrict__ eid_csr)
{
    int idx = blockIdx.x * blockDim.x + threadIdx.x;
    if (idx >= GG * EE) return;
    int g = idx / EE;
    int e = idx - g * EE;
    int d = dst[idx];
    int p = atomicAdd(&fill[g * NN + d], 1) + row_start[(size_t)g * (NN + 1) + d];
    src_csr[(size_t)g * EE + p] = src[idx];
    eid_csr[(size_t)g * EE + p] = e;
}

// ---------------------------------------------------------------------------
// Edge softmax per (layer, graph) in CSR order: thread per node segment
// ---------------------------------------------------------------------------
__global__ void edge_softmax_kernel(const float* __restrict__ e_edges,
                                    const int* __restrict__ eid_csr,
                                    const int* __restrict__ row_start,
                                    float* __restrict__ a_csr)
{
    int tid = blockIdx.x * blockDim.x + threadIdx.x;
    if (tid >= LL * GG * NN) return;
    int lg = tid / NN;             // l*G + g
    int v = tid - lg * NN;
    int g = lg % GG;
    const int* rs = row_start + (size_t)g * (NN + 1);
    int s = rs[v], tE = rs[v + 1];
    if (s >= tE) return;
    const int* eid = eid_csr + (size_t)g * EE;
    const float* ee = e_edges + (size_t)lg * EE;
    float* a = a_csr + (size_t)lg * EE;
    float m = -1e30f;
    for (int j = s; j < tE; j++) m = fmaxf(m, ee[eid[j]]);
    float sum = 0.f;
    for (int j = s; j < tE; j++) { float x = __expf(ee[eid[j]] - m); a[j] = x; sum += x; }
    float inv = 1.f / sum;
    for (int j = s; j < tE; j++) a[j] *= inv;
}

// ---------------------------------------------------------------------------
// Layer 0 propagation: wave per (g, node), lane = channel
// ---------------------------------------------------------------------------
__global__ __launch_bounds__(256) void prop0_kernel(
    const float* __restrict__ label_init, const float* __restrict__ labels_oh,
    const float* __restrict__ train_mask, const int* __restrict__ row_start,
    const int* __restrict__ src_csr, const float* __restrict__ a_csr,
    float* __restrict__ h_buf)
{
    int wid = (blockIdx.x * blockDim.x + threadIdx.x) >> 6;
    int lane = threadIdx.x & 63;
    if (wid >= GG * NN) return;
    int g = wid / NN;
    int v = wid - g * NN;
    const int* rs = row_start + (size_t)g * (NN + 1);
    int s = rs[v], tE = rs[v + 1];
    const float* a = a_csr + (size_t)g * EE;      // layer 0
    const int* sc = src_csr + (size_t)g * EE;
    float acc = 0.f;
    for (int base = s; base < tE; base += 64) {
        int j = base + lane;
        float aj = 0.f; int sj = 0;
        if (j < tE) { aj = a[j]; sj = sc[j]; }
        int cnt = min(64, tE - base);
        for (int k = 0; k < cnt; k++) {
            float ak = __shfl(aj, k);
            int sk = __shfl(sj, k);
            acc += label_init[(size_t)sk * 64 + lane] * ak;
        }
    }
    float tm = train_mask[v];
    float res = acc * (1.f - tm) + labels_oh[(size_t)v * 64 + lane] * tm;
    h_buf[(size_t)wid * 64 + lane] = res;
}

// ---------------------------------------------------------------------------
// Layer 1 + attention-weighted combine + alpha mix: wave per node
// ---------------------------------------------------------------------------
__global__ __launch_bounds__(256) void final_kernel(
    const float* __restrict__ h_buf, const float* __restrict__ labels_oh,
    const float* __restrict__ train_mask, const float* __restrict__ attention,
    const float* __restrict__ alpha, const int* __restrict__ row_start,
    const int* __restrict__ src_csr, const float* __restrict__ a_csr,
    const float* __restrict__ out_ns, float* __restrict__ out_logits,
    float* __restrict__ out_lp)
{
    int wid = (blockIdx.x * blockDim.x + threadIdx.x) >> 6;
    int lane = threadIdx.x & 63;
    if (wid >= NN) return;
    int v = wid;
    float tm = train_mask[v];
    float ml = 1.f - tm;
    float moh = labels_oh[(size_t)v * 64 + lane] * tm;
    float a0 = attention[v * 3], a1 = attention[v * 3 + 1], a2 = attention[v * 3 + 2];
    float mx = fmaxf(a0, fmaxf(a1, a2));
    float e0 = __expf(a0 - mx), e1 = __expf(a1 - mx), e2 = __expf(a2 - mx);
    float inv = 1.f / (e0 + e1 + e2);
    float attw0 = e0 * inv, attw1 = e1 * inv, attw2 = e2 * inv;
    float lp = 0.f;
    #pragma unroll
    for (int g = 0; g < GG; g++) {
        const int* rs = row_start + (size_t)g * (NN + 1);
        int s = rs[v], tE = rs[v + 1];
        const float* a = a_csr + (size_t)(GG + g) * EE;   // layer 1
        const int* sc = src_csr + (size_t)g * EE;
        const float* hin = h_buf + (size_t)g * NN * 64;
        float acc = 0.f;
        for (int base = s; base < tE; base += 64) {
            int j = base + lane;
            float aj = 0.f; int sj = 0;
            if (j < tE) { aj = a[j]; sj = sc[j]; }
            int cnt = min(64, tE - base);
            for (int k = 0; k < cnt; k++) {
                float ak = __shfl(aj, k);
                int sk = __shfl(sj, k);
                acc += hin[(size_t)sk * 64 + lane] * ak;
            }
        }
        float hf = acc * ml + moh;
        float w = (g == 0) ? attw0 : (g == 1) ? attw1 : attw2;
        lp += w * hf;
    }
    size_t o = (size_t)v * 64 + lane;
    out_lp[o] = lp;
    float al = alpha[v];
    float sg = 1.f / (1.f + __expf(-al));
    out_logits[o] = sg * lp + (1.f - sg) * out_ns[o];
}

// ---------------------------------------------------------------------------
extern "C" void kernel_launch(void* const* d_in, const int* in_sizes, int n_in,
                              void* d_out, int out_size, void* d_ws, size_t ws_size,
                              hipStream_t stream)
{
    const float* features0  = (const float*)d_in[0];
    const float* label_init = (const float*)d_in[1];
    const float* labels_oh  = (const float*)d_in[2];
    const float* train_mask = (const float*)d_in[3];
    const int*   src        = (const int*)d_in[4];
    const int*   dst        = (const int*)d_in[5];
    const float* e_edges    = (const float*)d_in[6];
    const float* attention  = (const float*)d_in[7];
    const float* alpha      = (const float*)d_in[8];
    const float* W1         = (const float*)d_in[9];
    const float* b1         = (const float*)d_in[10];
    const float* W2         = (const float*)d_in[11];
    const float* b2         = (const float*)d_in[12];

    float* out        = (float*)d_out;
    float* out_logits = out;
    float* out_lp     = out + (size_t)NN * CC;
    float* out_ns     = out + 2 * (size_t)NN * CC;

    char* base = (char*)d_ws;
    size_t off = 0;
    auto alloc = [&](size_t bytes) -> void* {
        void* p = base + off;
        off = (off + bytes + 255) & ~(size_t)255;
        return p;
    };
    int*   counts    = (int*)alloc((size_t)GG * NN * sizeof(int));
    int*   row_start = (int*)alloc((size_t)GG * (NN + 1) * sizeof(int));
    int*   src_csr   = (int*)alloc((size_t)GG * EE * sizeof(int));
    int*   eid_csr   = (int*)alloc((size_t)GG * EE * sizeof(int));
    float* a_csr     = (float*)alloc((size_t)LL * GG * EE * sizeof(float));
    float* h_buf     = (float*)alloc((size_t)GG * NN * CC * sizeof(float));
    // hm (GEMM1 output) is only live during the MLP phase, before any CSR
    // array is written; stream ordering makes full overlap with phase-2 safe.
    float* hm = (float*)d_ws;

    // ---- MLP: logits_ns = relu(features0 @ W1 + b1) @ W2 + b2 ----
    gemm_kernel<<<dim3((NN + 63) / 64, HH / 64), 256, 0, stream>>>(
        features0, W1, b1, hm, NN, HH, DD, 1);
    gemm_kernel<<<dim3((NN + 63) / 64, CC / 64), 256, 0, stream>>>(
        hm, W2, b2, out_ns, NN, CC, HH, 0);

    // ---- CSR build (per graph, fused over g in one grid) ----
    hipMemsetAsync(counts, 0, (size_t)GG * NN * sizeof(int), stream);
    hist_kernel<<<(GG * EE + 255) / 256, 256, 0, stream>>>(dst, counts);
    scan_kernel<<<GG, 256, 0, stream>>>(counts, row_start);
    hipMemsetAsync(counts, 0, (size_t)GG * NN * sizeof(int), stream);  // reuse as fill
    scatter_kernel<<<(GG * EE + 255) / 256, 256, 0, stream>>>(
        dst, src, row_start, counts, src_csr, eid_csr);

    // ---- Edge softmax for all (layer, graph) pairs ----
    edge_softmax_kernel<<<(LL * GG * NN + 255) / 256, 256, 0, stream>>>(
        e_edges, eid_csr, row_start, a_csr);

    // ---- Layer 0 propagation for all graphs ----
    prop0_kernel<<<((size_t)GG * NN * 64 + 255) / 256, 256, 0, stream>>>(
        label_init, labels_oh, train_mask, row_start, src_csr, a_csr, h_buf);

    // ---- Layer 1 + attention combine + alpha mix ----
    final_kernel<<<((size_t)NN * 64 + 255) / 256, 256, 0, stream>>>(
        h_buf, labels_oh, train_mask, attention, alpha, row_start, src_csr,
        a_csr, out_ns, out_logits, out_lp);
}

// Round 2
// 1463.002 us; speedup vs baseline: 1.1854x; 1.1854x over previous
//
#include <hip/hip_runtime.h>
#include <hip/hip_bf16.h>

#define NN 50000
#define CC 64
#define GG 3
#define EE 1200000
#define LL 2
#define DD 256
#define HH 256

// ---------------------------------------------------------------------------
// GEMM: C[M,Nc] = act(A[M,K] @ B[K,Nc] + bias), fp32, 64x64 tile, 4x4 micro
// ---------------------------------------------------------------------------
__global__ __launch_bounds__(256) void gemm_kernel(
    const float* __restrict__ A, const float* __restrict__ B,
    const float* __restrict__ bias, float* __restrict__ Cout,
    int M, int Nc, int K, int do_relu)
{
    __shared__ float As[16][68];
    __shared__ float Bs[16][64];
    int tid = threadIdx.x;
    int tx = tid & 15;
    int ty = tid >> 4;
    int m0 = blockIdx.x * 64;
    int n0 = blockIdx.y * 64;
    float acc[4][4] = {};

    for (int k0 = 0; k0 < K; k0 += 16) {
        {
            int kk = tid & 15;
            int mm = tid >> 4;
            #pragma unroll
            for (int i = 0; i < 4; i++) {
                int m = m0 + mm + i * 16;
                float v = (m < M) ? A[(size_t)m * K + k0 + kk] : 0.f;
                As[kk][mm + i * 16] = v;
            }
        }
        {
            int nn = tid & 63;
            int kk = tid >> 6;
            #pragma unroll
            for (int i = 0; i < 4; i++) {
                Bs[kk + i * 4][nn] = B[(size_t)(k0 + kk + i * 4) * Nc + n0 + nn];
            }
        }
        __syncthreads();
        #pragma unroll
        for (int kk = 0; kk < 16; kk++) {
            float4 a4 = *(const float4*)&As[kk][ty * 4];
            float4 b4 = *(const float4*)&Bs[kk][tx * 4];
            acc[0][0] += a4.x * b4.x; acc[0][1] += a4.x * b4.y;
            acc[0][2] += a4.x * b4.z; acc[0][3] += a4.x * b4.w;
            acc[1][0] += a4.y * b4.x; acc[1][1] += a4.y * b4.y;
            acc[1][2] += a4.y * b4.z; acc[1][3] += a4.y * b4.w;
            acc[2][0] += a4.z * b4.x; acc[2][1] += a4.z * b4.y;
            acc[2][2] += a4.z * b4.z; acc[2][3] += a4.z * b4.w;
            acc[3][0] += a4.w * b4.x; acc[3][1] += a4.w * b4.y;
            acc[3][2] += a4.w * b4.z; acc[3][3] += a4.w * b4.w;
        }
        __syncthreads();
    }
    #pragma unroll
    for (int i = 0; i < 4; i++) {
        int m = m0 + ty * 4 + i;
        if (m >= M) continue;
        #pragma unroll
        for (int j = 0; j < 4; j++) {
            int n = n0 + tx * 4 + j;
            float v = acc[i][j] + bias[n];
            if (do_relu) v = fmaxf(v, 0.f);
            Cout[(size_t)m * Nc + n] = v;
        }
    }
}

// ---------------------------------------------------------------------------
// CSR build
// ---------------------------------------------------------------------------
__global__ void hist_kernel(const int* __restrict__ dst, int* __restrict__ counts)
{
    int idx = blockIdx.x * blockDim.x + threadIdx.x;
    if (idx >= GG * EE) return;
    int g = idx / EE;
    atomicAdd(&counts[g * NN + dst[idx]], 1);
}

__global__ void scan_kernel(const int* __restrict__ counts, int* __restrict__ row_start)
{
    int g = blockIdx.x;
    const int* cnt = counts + (size_t)g * NN;
    int* rs = row_start + (size_t)g * (NN + 1);
    __shared__ int sdata[256];
    __shared__ int s_running;
    int t = threadIdx.x;
    if (t == 0) s_running = 0;
    __syncthreads();
    for (int base = 0; base < NN; base += 256) {
        int i = base + t;
        int v = (i < NN) ? cnt[i] : 0;
        sdata[t] = v;
        __syncthreads();
        for (int offp = 1; offp < 256; offp <<= 1) {
            int x = (t >= offp) ? sdata[t - offp] : 0;
            __syncthreads();
            sdata[t] += x;
            __syncthreads();
        }
        int incl = sdata[t];
        int run = s_running;
        __syncthreads();
        if (i < NN) rs[i] = run + incl - v;       // exclusive
        if (t == 255) s_running = run + sdata[255];
        __syncthreads();
    }
    if (t == 0) rs[NN] = s_running;
}

// Scatter edges into CSR order; also permute BOTH layers' edge logits into
// CSR slots so no eid indirection is ever needed downstream. Reads of
// e_edges are coalesced; the random 4B CSR writes get merged in L2/L3.
__global__ void scatter_kernel(const int* __restrict__ dst, const int* __restrict__ src,
                               const float* __restrict__ e_edges,
                               const int* __restrict__ row_start, int* __restrict__ fill,
                               int* __restrict__ src_csr, float* __restrict__ a_csr)
{
    int idx = blockIdx.x * blockDim.x + threadIdx.x;
    if (idx >= GG * EE) return;
    int g = idx / EE;
    int e = idx - g * EE;
    int d = dst[idx];
    int p = atomicAdd(&fill[g * NN + d], 1) + row_start[(size_t)g * (NN + 1) + d];
    src_csr[(size_t)g * EE + p] = src[idx];
    a_csr[(size_t)g * EE + p]        = e_edges[(size_t)g * EE + e];        // layer 0
    a_csr[(size_t)(GG + g) * EE + p] = e_edges[(size_t)(GG + g) * EE + e]; // layer 1
}

// ---------------------------------------------------------------------------
// Edge softmax, in place on CSR-ordered logits: one wave per (layer,graph,node).
// Contiguous segment -> fully coalesced; shuffle reductions; in-place safe
// (each element is read before it is overwritten).
// ---------------------------------------------------------------------------
__global__ __launch_bounds__(256) void edge_softmax_kernel(
    const int* __restrict__ row_start, float* __restrict__ a_csr)
{
    int wid = (blockIdx.x * blockDim.x + threadIdx.x) >> 6;
    int lane = threadIdx.x & 63;
    if (wid >= LL * GG * NN) return;
    int lg = wid / NN;
    int v = wid - lg * NN;
    int g = lg % GG;
    const int* rs = row_start + (size_t)g * (NN + 1);
    int s = rs[v], tE = rs[v + 1];
    if (s >= tE) return;
    float* a = a_csr + (size_t)lg * EE;

    float m = -1e30f;
    for (int base = s; base < tE; base += 64) {
        int j = base + lane;
        if (j < tE) m = fmaxf(m, a[j]);
    }
    #pragma unroll
    for (int off = 32; off; off >>= 1) m = fmaxf(m, __shfl_xor(m, off));

    float sum = 0.f;
    for (int base = s; base < tE; base += 64) {
        int j = base + lane;
        if (j < tE) sum += __expf(a[j] - m);
    }
    #pragma unroll
    for (int off = 32; off; off >>= 1) sum += __shfl_xor(sum, off);
    float inv = 1.f / sum;

    for (int base = s; base < tE; base += 64) {
        int j = base + lane;
        if (j < tE) a[j] = __expf(a[j] - m) * inv;
    }
}

// ---------------------------------------------------------------------------
// Layer 0 propagation: wave per (g, node), lane = channel
// ---------------------------------------------------------------------------
__global__ __launch_bounds__(256) void prop0_kernel(
    const float* __restrict__ label_init, const float* __restrict__ labels_oh,
    const float* __restrict__ train_mask, const int* __restrict__ row_start,
    const int* __restrict__ src_csr, const float* __restrict__ a_csr,
    float* __restrict__ h_buf)
{
    int wid = (blockIdx.x * blockDim.x + threadIdx.x) >> 6;
    int lane = threadIdx.x & 63;
    if (wid >= GG * NN) return;
    int g = wid / NN;
    int v = wid - g * NN;
    const int* rs = row_start + (size_t)g * (NN + 1);
    int s = rs[v], tE = rs[v + 1];
    const float* a = a_csr + (size_t)g * EE;      // layer 0
    const int* sc = src_csr + (size_t)g * EE;
    float acc = 0.f;
    for (int base = s; base < tE; base += 64) {
        int j = base + lane;
        float aj = 0.f; int sj = 0;
        if (j < tE) { aj = a[j]; sj = sc[j]; }
        int cnt = min(64, tE - base);
        for (int k = 0; k < cnt; k++) {
            float ak = __shfl(aj, k);
            int sk = __shfl(sj, k);
            acc += label_init[(size_t)sk * 64 + lane] * ak;
        }
    }
    float tm = train_mask[v];
    float res = acc * (1.f - tm) + labels_oh[(size_t)v * 64 + lane] * tm;
    h_buf[(size_t)wid * 64 + lane] = res;
}

// ---------------------------------------------------------------------------
// Layer 1 + attention-weighted combine + alpha mix: wave per node
// ---------------------------------------------------------------------------
__global__ __launch_bounds__(256) void final_kernel(
    const float* __restrict__ h_buf, const float* __restrict__ labels_oh,
    const float* __restrict__ train_mask, const float* __restrict__ attention,
    const float* __restrict__ alpha, const int* __restrict__ row_start,
    const int* __restrict__ src_csr, const float* __restrict__ a_csr,
    const float* __restrict__ out_ns, float* __restrict__ out_logits,
    float* __restrict__ out_lp)
{
    int wid = (blockIdx.x * blockDim.x + threadIdx.x) >> 6;
    int lane = threadIdx.x & 63;
    if (wid >= NN) return;
    int v = wid;
    float tm = train_mask[v];
    float ml = 1.f - tm;
    float moh = labels_oh[(size_t)v * 64 + lane] * tm;
    float a0 = attention[v * 3], a1 = attention[v * 3 + 1], a2 = attention[v * 3 + 2];
    float mx = fmaxf(a0, fmaxf(a1, a2));
    float e0 = __expf(a0 - mx), e1 = __expf(a1 - mx), e2 = __expf(a2 - mx);
    float inv = 1.f / (e0 + e1 + e2);
    float attw0 = e0 * inv, attw1 = e1 * inv, attw2 = e2 * inv;
    float lp = 0.f;
    #pragma unroll
    for (int g = 0; g < GG; g++) {
        const int* rs = row_start + (size_t)g * (NN + 1);
        int s = rs[v], tE = rs[v + 1];
        const float* a = a_csr + (size_t)(GG + g) * EE;   // layer 1
        const int* sc = src_csr + (size_t)g * EE;
        const float* hin = h_buf + (size_t)g * NN * 64;
        float acc = 0.f;
        for (int base = s; base < tE; base += 64) {
            int j = base + lane;
            float aj = 0.f; int sj = 0;
            if (j < tE) { aj = a[j]; sj = sc[j]; }
            int cnt = min(64, tE - base);
            for (int k = 0; k < cnt; k++) {
                float ak = __shfl(aj, k);
                int sk = __shfl(sj, k);
                acc += hin[(size_t)sk * 64 + lane] * ak;
            }
        }
        float hf = acc * ml + moh;
        float w = (g == 0) ? attw0 : (g == 1) ? attw1 : attw2;
        lp += w * hf;
    }
    size_t o = (size_t)v * 64 + lane;
    out_lp[o] = lp;
    float al = alpha[v];
    float sg = 1.f / (1.f + __expf(-al));
    out_logits[o] = sg * lp + (1.f - sg) * out_ns[o];
}

// ---------------------------------------------------------------------------
extern "C" void kernel_launch(void* const* d_in, const int* in_sizes, int n_in,
                              void* d_out, int out_size, void* d_ws, size_t ws_size,
                              hipStream_t stream)
{
    const float* features0  = (const float*)d_in[0];
    const float* label_init = (const float*)d_in[1];
    const float* labels_oh  = (const float*)d_in[2];
    const float* train_mask = (const float*)d_in[3];
    const int*   src        = (const int*)d_in[4];
    const int*   dst        = (const int*)d_in[5];
    const float* e_edges    = (const float*)d_in[6];
    const float* attention  = (const float*)d_in[7];
    const float* alpha      = (const float*)d_in[8];
    const float* W1         = (const float*)d_in[9];
    const float* b1         = (const float*)d_in[10];
    const float* W2         = (const float*)d_in[11];
    const float* b2         = (const float*)d_in[12];

    float* out        = (float*)d_out;
    float* out_logits = out;
    float* out_lp     = out + (size_t)NN * CC;
    float* out_ns     = out + 2 * (size_t)NN * CC;

    char* base = (char*)d_ws;
    size_t off = 0;
    auto alloc = [&](size_t bytes) -> void* {
        void* p = base + off;
        off = (off + bytes + 255) & ~(size_t)255;
        return p;
    };
    int*   counts    = (int*)alloc((size_t)GG * NN * sizeof(int));
    int*   row_start = (int*)alloc((size_t)GG * (NN + 1) * sizeof(int));
    int*   src_csr   = (int*)alloc((size_t)GG * EE * sizeof(int));
    float* a_csr     = (float*)alloc((size_t)LL * GG * EE * sizeof(float));  // logits -> softmax in place
    float* h_buf     = (float*)alloc((size_t)GG * NN * CC * sizeof(float));
    // hm (GEMM1 output) is only live during the MLP phase, before any CSR
    // array is written; stream ordering makes full overlap with phase-2 safe.
    float* hm = (float*)d_ws;

    // ---- MLP: logits_ns = relu(features0 @ W1 + b1) @ W2 + b2 ----
    gemm_kernel<<<dim3((NN + 63) / 64, HH / 64), 256, 0, stream>>>(
        features0, W1, b1, hm, NN, HH, DD, 1);
    gemm_kernel<<<dim3((NN + 63) / 64, CC / 64), 256, 0, stream>>>(
        hm, W2, b2, out_ns, NN, CC, HH, 0);

    // ---- CSR build (per graph, fused over g in one grid) ----
    hipMemsetAsync(counts, 0, (size_t)GG * NN * sizeof(int), stream);
    hist_kernel<<<(GG * EE + 255) / 256, 256, 0, stream>>>(dst, counts);
    scan_kernel<<<GG, 256, 0, stream>>>(counts, row_start);
    hipMemsetAsync(counts, 0, (size_t)GG * NN * sizeof(int), stream);  // reuse as fill
    scatter_kernel<<<(GG * EE + 255) / 256, 256, 0, stream>>>(
        dst, src, e_edges, row_start, counts, src_csr, a_csr);

    // ---- Edge softmax for all (layer, graph) pairs, in place, wave/node ----
    edge_softmax_kernel<<<((size_t)LL * GG * NN * 64 + 255) / 256, 256, 0, stream>>>(
        row_start, a_csr);

    // ---- Layer 0 propagation for all graphs ----
    prop0_kernel<<<((size_t)GG * NN * 64 + 255) / 256, 256, 0, stream>>>(
        label_init, labels_oh, train_mask, row_start, src_csr, a_csr, h_buf);

    // ---- Layer 1 + attention combine + alpha mix ----
    final_kernel<<<((size_t)NN * 64 + 255) / 256, 256, 0, stream>>>(
        h_buf, labels_oh, train_mask, attention, alpha, row_start, src_csr,
        a_csr, out_ns, out_logits, out_lp);
}

// Round 3
// 1057.781 us; speedup vs baseline: 1.6395x; 1.3831x over previous
//
#include <hip/hip_runtime.h>
#include <hip/hip_bf16.h>

#define NN 50000
#define CC 64
#define GG 3
#define EE 1200000
#define LL 2
#define DD 256
#define HH 256
#define NCHUNK 196   // ceil(NN/256)

// Edge record, CSR-ordered: one float4 = {e0 logit, e1 logit, src (bits), pad}
// Single 16B random write at build; read-only afterwards.

// ---------------------------------------------------------------------------
// GEMM: C[M,Nc] = act(A[M,K] @ B[K,Nc] + bias), fp32, 64x64 tile, 4x4 micro
// ---------------------------------------------------------------------------
__global__ __launch_bounds__(256) void gemm_kernel(
    const float* __restrict__ A, const float* __restrict__ B,
    const float* __restrict__ bias, float* __restrict__ Cout,
    int M, int Nc, int K, int do_relu)
{
    __shared__ float As[16][68];
    __shared__ float Bs[16][64];
    int tid = threadIdx.x;
    int tx = tid & 15;
    int ty = tid >> 4;
    int m0 = blockIdx.x * 64;
    int n0 = blockIdx.y * 64;
    float acc[4][4] = {};

    for (int k0 = 0; k0 < K; k0 += 16) {
        {
            int kk = tid & 15;
            int mm = tid >> 4;
            #pragma unroll
            for (int i = 0; i < 4; i++) {
                int m = m0 + mm + i * 16;
                float v = (m < M) ? A[(size_t)m * K + k0 + kk] : 0.f;
                As[kk][mm + i * 16] = v;
            }
        }
        {
            int nn = tid & 63;
            int kk = tid >> 6;
            #pragma unroll
            for (int i = 0; i < 4; i++) {
                Bs[kk + i * 4][nn] = B[(size_t)(k0 + kk + i * 4) * Nc + n0 + nn];
            }
        }
        __syncthreads();
        #pragma unroll
        for (int kk = 0; kk < 16; kk++) {
            float4 a4 = *(const float4*)&As[kk][ty * 4];
            float4 b4 = *(const float4*)&Bs[kk][tx * 4];
            acc[0][0] += a4.x * b4.x; acc[0][1] += a4.x * b4.y;
            acc[0][2] += a4.x * b4.z; acc[0][3] += a4.x * b4.w;
            acc[1][0] += a4.y * b4.x; acc[1][1] += a4.y * b4.y;
            acc[1][2] += a4.y * b4.z; acc[1][3] += a4.y * b4.w;
            acc[2][0] += a4.z * b4.x; acc[2][1] += a4.z * b4.y;
            acc[2][2] += a4.z * b4.z; acc[2][3] += a4.z * b4.w;
            acc[3][0] += a4.w * b4.x; acc[3][1] += a4.w * b4.y;
            acc[3][2] += a4.w * b4.z; acc[3][3] += a4.w * b4.w;
        }
        __syncthreads();
    }
    #pragma unroll
    for (int i = 0; i < 4; i++) {
        int m = m0 + ty * 4 + i;
        if (m >= M) continue;
        #pragma unroll
        for (int j = 0; j < 4; j++) {
            int n = n0 + tx * 4 + j;
            float v = acc[i][j] + bias[n];
            if (do_relu) v = fmaxf(v, 0.f);
            Cout[(size_t)m * Nc + n] = v;
        }
    }
}

// ---------------------------------------------------------------------------
// CSR build
// ---------------------------------------------------------------------------
__global__ void hist_kernel(const int* __restrict__ dst, int* __restrict__ counts)
{
    int idx = blockIdx.x * blockDim.x + threadIdx.x;
    if (idx >= GG * EE) return;
    int g = idx / EE;
    atomicAdd(&counts[g * NN + dst[idx]], 1);
}

// 3-phase parallel exclusive scan of counts -> row_start (per graph)
__global__ void scan_phase1(const int* __restrict__ counts, int* __restrict__ rs,
                            int* __restrict__ block_sums)
{
    int b = blockIdx.x;              // 0 .. G*NCHUNK-1
    int g = b / NCHUNK;
    int c = b - g * NCHUNK;
    int t = threadIdx.x;
    int i = c * 256 + t;
    __shared__ int sd[256];
    int v = (i < NN) ? counts[(size_t)g * NN + i] : 0;
    sd[t] = v;
    __syncthreads();
    for (int off = 1; off < 256; off <<= 1) {
        int x = (t >= off) ? sd[t - off] : 0;
        __syncthreads();
        sd[t] += x;
        __syncthreads();
    }
    if (i < NN) rs[(size_t)g * (NN + 1) + i] = sd[t] - v;   // local exclusive
    if (t == 255) block_sums[b] = sd[255];
}

__global__ void scan_phase2(const int* __restrict__ block_sums,
                            int* __restrict__ chunk_off, int* __restrict__ rs)
{
    int g = blockIdx.x;
    int t = threadIdx.x;
    __shared__ int sd[256];
    int v = (t < NCHUNK) ? block_sums[g * NCHUNK + t] : 0;
    sd[t] = v;
    __syncthreads();
    for (int off = 1; off < 256; off <<= 1) {
        int x = (t >= off) ? sd[t - off] : 0;
        __syncthreads();
        sd[t] += x;
        __syncthreads();
    }
    if (t < NCHUNK) chunk_off[g * NCHUNK + t] = sd[t] - v;
    if (t == 255) rs[(size_t)g * (NN + 1) + NN] = sd[255];
}

__global__ void scan_phase3(int* __restrict__ rs, const int* __restrict__ chunk_off)
{
    int b = blockIdx.x;
    int g = b / NCHUNK;
    int c = b - g * NCHUNK;
    int i = c * 256 + threadIdx.x;
    if (i < NN) rs[(size_t)g * (NN + 1) + i] += chunk_off[g * NCHUNK + c];
}

// Scatter each edge's full record (both layers' logits + src) as ONE 16B
// random write. Reads coalesced; fill/row_start are L2-resident (600 KB).
__global__ void scatter_kernel(const int* __restrict__ dst, const int* __restrict__ src,
                               const float* __restrict__ e_edges,
                               const int* __restrict__ row_start, int* __restrict__ fill,
                               float4* __restrict__ edges)
{
    int idx = blockIdx.x * blockDim.x + threadIdx.x;
    if (idx >= GG * EE) return;
    int g = idx / EE;
    int e = idx - g * EE;
    int d = dst[idx];
    int p = atomicAdd(&fill[g * NN + d], 1) + row_start[(size_t)g * (NN + 1) + d];
    float4 rec;
    rec.x = e_edges[(size_t)g * EE + e];          // layer 0 logit
    rec.y = e_edges[(size_t)(GG + g) * EE + e];   // layer 1 logit
    rec.z = __int_as_float(src[idx]);
    rec.w = 0.f;
    edges[(size_t)g * EE + p] = rec;
}

// ---------------------------------------------------------------------------
// Layer 0 propagation + fused online edge-softmax: wave per (g, node)
// ---------------------------------------------------------------------------
__global__ __launch_bounds__(256) void prop0_kernel(
    const float* __restrict__ label_init, const float* __restrict__ labels_oh,
    const float* __restrict__ train_mask, const int* __restrict__ row_start,
    const float4* __restrict__ edges, float* __restrict__ h_buf)
{
    int wid = (blockIdx.x * blockDim.x + threadIdx.x) >> 6;
    int lane = threadIdx.x & 63;
    if (wid >= GG * NN) return;
    int g = wid / NN;
    int v = wid - g * NN;
    const int* rs = row_start + (size_t)g * (NN + 1);
    int s = rs[v], tE = rs[v + 1];
    const float4* eg = edges + (size_t)g * EE;

    // online softmax stats over the segment (lane-strided, then butterfly)
    float m = -1e30f, sum = 0.f;
    for (int j = s + lane; j < tE; j += 64) {
        float e0 = eg[j].x;
        float mn = fmaxf(m, e0);
        sum = sum * __expf(m - mn) + __expf(e0 - mn);
        m = mn;
    }
    #pragma unroll
    for (int off = 32; off; off >>= 1) {
        float mo = __shfl_xor(m, off);
        float so = __shfl_xor(sum, off);
        float mn = fmaxf(m, mo);
        sum = sum * __expf(m - mn) + so * __expf(mo - mn);
        m = mn;
    }
    float inv = 1.f / sum;

    float acc = 0.f;
    for (int base = s; base < tE; base += 64) {
        int j = base + lane;
        float aj = 0.f; int sj = 0;
        if (j < tE) {
            float4 r = eg[j];
            aj = __expf(r.x - m) * inv;
            sj = __float_as_int(r.z);
        }
        int cnt = min(64, tE - base);
        for (int k = 0; k < cnt; k++) {
            float ak = __shfl(aj, k);
            int sk = __shfl(sj, k);
            acc += label_init[(size_t)sk * 64 + lane] * ak;
        }
    }
    float tm = train_mask[v];
    float res = acc * (1.f - tm) + labels_oh[(size_t)v * 64 + lane] * tm;
    h_buf[(size_t)wid * 64 + lane] = res;
}

// ---------------------------------------------------------------------------
// Layer 1 (fused softmax) + attention combine + alpha mix: wave per node
// ---------------------------------------------------------------------------
__global__ __launch_bounds__(256) void final_kernel(
    const float* __restrict__ h_buf, const float* __restrict__ labels_oh,
    const float* __restrict__ train_mask, const float* __restrict__ attention,
    const float* __restrict__ alpha, const int* __restrict__ row_start,
    const float4* __restrict__ edges, const float* __restrict__ out_ns,
    float* __restrict__ out_logits, float* __restrict__ out_lp)
{
    int wid = (blockIdx.x * blockDim.x + threadIdx.x) >> 6;
    int lane = threadIdx.x & 63;
    if (wid >= NN) return;
    int v = wid;
    float tm = train_mask[v];
    float ml = 1.f - tm;
    float moh = labels_oh[(size_t)v * 64 + lane] * tm;
    float a0 = attention[v * 3], a1 = attention[v * 3 + 1], a2 = attention[v * 3 + 2];
    float mx = fmaxf(a0, fmaxf(a1, a2));
    float e0 = __expf(a0 - mx), e1 = __expf(a1 - mx), e2 = __expf(a2 - mx);
    float ainv = 1.f / (e0 + e1 + e2);
    float attw[3] = {e0 * ainv, e1 * ainv, e2 * ainv};
    float lp = 0.f;
    #pragma unroll
    for (int g = 0; g < GG; g++) {
        const int* rs = row_start + (size_t)g * (NN + 1);
        int s = rs[v], tE = rs[v + 1];
        const float4* eg = edges + (size_t)g * EE;
        const float* hin = h_buf + (size_t)g * NN * 64;

        float m = -1e30f, sum = 0.f;
        for (int j = s + lane; j < tE; j += 64) {
            float ev = eg[j].y;
            float mn = fmaxf(m, ev);
            sum = sum * __expf(m - mn) + __expf(ev - mn);
            m = mn;
        }
        #pragma unroll
        for (int off = 32; off; off >>= 1) {
            float mo = __shfl_xor(m, off);
            float so = __shfl_xor(sum, off);
            float mn = fmaxf(m, mo);
            sum = sum * __expf(m - mn) + so * __expf(mo - mn);
            m = mn;
        }
        float inv = 1.f / sum;

        float acc = 0.f;
        for (int base = s; base < tE; base += 64) {
            int j = base + lane;
            float aj = 0.f; int sj = 0;
            if (j < tE) {
                float4 r = eg[j];
                aj = __expf(r.y - m) * inv;
                sj = __float_as_int(r.z);
            }
            int cnt = min(64, tE - base);
            for (int k = 0; k < cnt; k++) {
                float ak = __shfl(aj, k);
                int sk = __shfl(sj, k);
                acc += hin[(size_t)sk * 64 + lane] * ak;
            }
        }
        float hf = acc * ml + moh;
        lp += attw[g] * hf;
    }
    size_t o = (size_t)v * 64 + lane;
    out_lp[o] = lp;
    float al = alpha[v];
    float sg = 1.f / (1.f + __expf(-al));
    out_logits[o] = sg * lp + (1.f - sg) * out_ns[o];
}

// ---------------------------------------------------------------------------
extern "C" void kernel_launch(void* const* d_in, const int* in_sizes, int n_in,
                              void* d_out, int out_size, void* d_ws, size_t ws_size,
                              hipStream_t stream)
{
    const float* features0  = (const float*)d_in[0];
    const float* label_init = (const float*)d_in[1];
    const float* labels_oh  = (const float*)d_in[2];
    const float* train_mask = (const float*)d_in[3];
    const int*   src        = (const int*)d_in[4];
    const int*   dst        = (const int*)d_in[5];
    const float* e_edges    = (const float*)d_in[6];
    const float* attention  = (const float*)d_in[7];
    const float* alpha      = (const float*)d_in[8];
    const float* W1         = (const float*)d_in[9];
    const float* b1         = (const float*)d_in[10];
    const float* W2         = (const float*)d_in[11];
    const float* b2         = (const float*)d_in[12];

    float* out        = (float*)d_out;
    float* out_logits = out;
    float* out_lp     = out + (size_t)NN * CC;
    float* out_ns     = out + 2 * (size_t)NN * CC;

    char* base = (char*)d_ws;
    size_t off = 0;
    auto alloc = [&](size_t bytes) -> void* {
        void* p = base + off;
        off = (off + bytes + 255) & ~(size_t)255;
        return p;
    };
    int*    counts     = (int*)alloc((size_t)GG * NN * sizeof(int));
    int*    row_start  = (int*)alloc((size_t)GG * (NN + 1) * sizeof(int));
    int*    block_sums = (int*)alloc((size_t)GG * NCHUNK * sizeof(int));
    int*    chunk_off  = (int*)alloc((size_t)GG * NCHUNK * sizeof(int));
    float4* edges      = (float4*)alloc((size_t)GG * EE * sizeof(float4));
    float*  h_buf      = (float*)alloc((size_t)GG * NN * CC * sizeof(float));
    // hm (GEMM1 output) only lives during the MLP phase, which completes
    // (stream-ordered) before any CSR array is written -> overlap is safe.
    float* hm = (float*)d_ws;

    // ---- MLP: logits_ns = relu(features0 @ W1 + b1) @ W2 + b2 ----
    gemm_kernel<<<dim3((NN + 63) / 64, HH / 64), 256, 0, stream>>>(
        features0, W1, b1, hm, NN, HH, DD, 1);
    gemm_kernel<<<dim3((NN + 63) / 64, CC / 64), 256, 0, stream>>>(
        hm, W2, b2, out_ns, NN, CC, HH, 0);

    // ---- CSR build ----
    hipMemsetAsync(counts, 0, (size_t)GG * NN * sizeof(int), stream);
    hist_kernel<<<(GG * EE + 255) / 256, 256, 0, stream>>>(dst, counts);
    scan_phase1<<<GG * NCHUNK, 256, 0, stream>>>(counts, row_start, block_sums);
    scan_phase2<<<GG, 256, 0, stream>>>(block_sums, chunk_off, row_start);
    scan_phase3<<<GG * NCHUNK, 256, 0, stream>>>(row_start, chunk_off);
    hipMemsetAsync(counts, 0, (size_t)GG * NN * sizeof(int), stream);  // reuse as fill
    scatter_kernel<<<(GG * EE + 255) / 256, 256, 0, stream>>>(
        dst, src, e_edges, row_start, counts, edges);

    // ---- Layer 0 propagation (fused edge softmax) ----
    prop0_kernel<<<((size_t)GG * NN * 64 + 255) / 256, 256, 0, stream>>>(
        label_init, labels_oh, train_mask, row_start, edges, h_buf);

    // ---- Layer 1 (fused softmax) + attention combine + alpha mix ----
    final_kernel<<<((size_t)NN * 64 + 255) / 256, 256, 0, stream>>>(
        h_buf, labels_oh, train_mask, attention, alpha, row_start, edges,
        out_ns, out_logits, out_lp);
}

// Round 4
// 1046.125 us; speedup vs baseline: 1.6578x; 1.0111x over previous
//
#include <hip/hip_runtime.h>
#include <hip/hip_bf16.h>

#define NN 50000
#define CC 64
#define GG 3
#define EE 1200000
#define LL 2
#define DD 256
#define HH 256
#define NCHUNK 196   // ceil(NN/256)

// Edge record, CSR-ordered: float4 = {e0 logit, e1 logit, src (int bits), pad}.
// One 16B random write at build; read-only afterwards.
// Gather tables (label_init, h_buf) are bf16 (ushort): 128B rows.

__device__ __forceinline__ ushort f2bf(float f) {
    unsigned b = __float_as_uint(f);
    return (ushort)((b + 0x7fffu + ((b >> 16) & 1u)) >> 16);
}
__device__ __forceinline__ float bf2f(ushort u) {
    return __uint_as_float(((unsigned)u) << 16);
}

// ---------------------------------------------------------------------------
// GEMM: C[M,Nc] = act(A[M,K] @ B[K,Nc] + bias), fp32, 64x64 tile, 4x4 micro
// ---------------------------------------------------------------------------
__global__ __launch_bounds__(256) void gemm_kernel(
    const float* __restrict__ A, const float* __restrict__ B,
    const float* __restrict__ bias, float* __restrict__ Cout,
    int M, int Nc, int K, int do_relu)
{
    __shared__ float As[16][68];
    __shared__ float Bs[16][64];
    int tid = threadIdx.x;
    int tx = tid & 15;
    int ty = tid >> 4;
    int m0 = blockIdx.x * 64;
    int n0 = blockIdx.y * 64;
    float acc[4][4] = {};

    for (int k0 = 0; k0 < K; k0 += 16) {
        {
            int kk = tid & 15;
            int mm = tid >> 4;
            #pragma unroll
            for (int i = 0; i < 4; i++) {
                int m = m0 + mm + i * 16;
                float v = (m < M) ? A[(size_t)m * K + k0 + kk] : 0.f;
                As[kk][mm + i * 16] = v;
            }
        }
        {
            int nn = tid & 63;
            int kk = tid >> 6;
            #pragma unroll
            for (int i = 0; i < 4; i++) {
                Bs[kk + i * 4][nn] = B[(size_t)(k0 + kk + i * 4) * Nc + n0 + nn];
            }
        }
        __syncthreads();
        #pragma unroll
        for (int kk = 0; kk < 16; kk++) {
            float4 a4 = *(const float4*)&As[kk][ty * 4];
            float4 b4 = *(const float4*)&Bs[kk][tx * 4];
            acc[0][0] += a4.x * b4.x; acc[0][1] += a4.x * b4.y;
            acc[0][2] += a4.x * b4.z; acc[0][3] += a4.x * b4.w;
            acc[1][0] += a4.y * b4.x; acc[1][1] += a4.y * b4.y;
            acc[1][2] += a4.y * b4.z; acc[1][3] += a4.y * b4.w;
            acc[2][0] += a4.z * b4.x; acc[2][1] += a4.z * b4.y;
            acc[2][2] += a4.z * b4.z; acc[2][3] += a4.z * b4.w;
            acc[3][0] += a4.w * b4.x; acc[3][1] += a4.w * b4.y;
            acc[3][2] += a4.w * b4.z; acc[3][3] += a4.w * b4.w;
        }
        __syncthreads();
    }
    #pragma unroll
    for (int i = 0; i < 4; i++) {
        int m = m0 + ty * 4 + i;
        if (m >= M) continue;
        #pragma unroll
        for (int j = 0; j < 4; j++) {
            int n = n0 + tx * 4 + j;
            float v = acc[i][j] + bias[n];
            if (do_relu) v = fmaxf(v, 0.f);
            Cout[(size_t)m * Nc + n] = v;
        }
    }
}

// ---------------------------------------------------------------------------
// fp32 -> bf16 table conversion (vectorized 4-wide)
// ---------------------------------------------------------------------------
__global__ void cvt_kernel(const float* __restrict__ in, ushort* __restrict__ out, int n4)
{
    int i = blockIdx.x * blockDim.x + threadIdx.x;
    if (i >= n4) return;
    float4 f = ((const float4*)in)[i];
    ushort4 u;
    u.x = f2bf(f.x); u.y = f2bf(f.y); u.z = f2bf(f.z); u.w = f2bf(f.w);
    ((ushort4*)out)[i] = u;
}

// ---------------------------------------------------------------------------
// CSR build
// ---------------------------------------------------------------------------
__global__ void hist_kernel(const int* __restrict__ dst, int* __restrict__ counts)
{
    int idx = blockIdx.x * blockDim.x + threadIdx.x;
    if (idx >= GG * EE) return;
    int g = idx / EE;
    atomicAdd(&counts[g * NN + dst[idx]], 1);
}

__global__ void scan_phase1(const int* __restrict__ counts, int* __restrict__ rs,
                            int* __restrict__ block_sums)
{
    int b = blockIdx.x;
    int g = b / NCHUNK;
    int c = b - g * NCHUNK;
    int t = threadIdx.x;
    int i = c * 256 + t;
    __shared__ int sd[256];
    int v = (i < NN) ? counts[(size_t)g * NN + i] : 0;
    sd[t] = v;
    __syncthreads();
    for (int off = 1; off < 256; off <<= 1) {
        int x = (t >= off) ? sd[t - off] : 0;
        __syncthreads();
        sd[t] += x;
        __syncthreads();
    }
    if (i < NN) rs[(size_t)g * (NN + 1) + i] = sd[t] - v;
    if (t == 255) block_sums[b] = sd[255];
}

__global__ void scan_phase2(const int* __restrict__ block_sums,
                            int* __restrict__ chunk_off, int* __restrict__ rs)
{
    int g = blockIdx.x;
    int t = threadIdx.x;
    __shared__ int sd[256];
    int v = (t < NCHUNK) ? block_sums[g * NCHUNK + t] : 0;
    sd[t] = v;
    __syncthreads();
    for (int off = 1; off < 256; off <<= 1) {
        int x = (t >= off) ? sd[t - off] : 0;
        __syncthreads();
        sd[t] += x;
        __syncthreads();
    }
    if (t < NCHUNK) chunk_off[g * NCHUNK + t] = sd[t] - v;
    if (t == 255) rs[(size_t)g * (NN + 1) + NN] = sd[255];
}

__global__ void scan_phase3(int* __restrict__ rs, const int* __restrict__ chunk_off)
{
    int b = blockIdx.x;
    int g = b / NCHUNK;
    int c = b - g * NCHUNK;
    int i = c * 256 + threadIdx.x;
    if (i < NN) rs[(size_t)g * (NN + 1) + i] += chunk_off[g * NCHUNK + c];
}

__global__ void scatter_kernel(const int* __restrict__ dst, const int* __restrict__ src,
                               const float* __restrict__ e_edges,
                               const int* __restrict__ row_start, int* __restrict__ fill,
                               float4* __restrict__ edges)
{
    int idx = blockIdx.x * blockDim.x + threadIdx.x;
    if (idx >= GG * EE) return;
    int g = idx / EE;
    int e = idx - g * EE;
    int d = dst[idx];
    int p = atomicAdd(&fill[g * NN + d], 1) + row_start[(size_t)g * (NN + 1) + d];
    float4 rec;
    rec.x = e_edges[(size_t)g * EE + e];
    rec.y = e_edges[(size_t)(GG + g) * EE + e];
    rec.z = __int_as_float(src[idx]);
    rec.w = 0.f;
    edges[(size_t)g * EE + p] = rec;
}

// ---------------------------------------------------------------------------
// Layer 0 propagation + fused L0 softmax + L1 softmax stats: wave per (g,node)
// ---------------------------------------------------------------------------
__global__ __launch_bounds__(256) void prop0_kernel(
    const ushort* __restrict__ lab_bf, const float* __restrict__ labels_oh,
    const float* __restrict__ train_mask, const int* __restrict__ row_start,
    const float4* __restrict__ edges, ushort* __restrict__ h_buf,
    float2* __restrict__ stat1)
{
    int wid = (blockIdx.x * blockDim.x + threadIdx.x) >> 6;
    int lane = threadIdx.x & 63;
    if (wid >= GG * NN) return;
    int g = wid / NN;
    int v = wid - g * NN;
    const int* rs = row_start + (size_t)g * (NN + 1);
    int s = rs[v], tE = rs[v + 1];
    const float4* eg = edges + (size_t)g * EE;

    // layer-0 softmax stats (lane-strided online, then butterfly)
    float m = -1e30f, sum = 0.f;
    for (int j = s + lane; j < tE; j += 64) {
        float e0 = eg[j].x;
        float mn = fmaxf(m, e0);
        sum = sum * __expf(m - mn) + __expf(e0 - mn);
        m = mn;
    }
    #pragma unroll
    for (int off = 32; off; off >>= 1) {
        float mo = __shfl_xor(m, off);
        float so = __shfl_xor(sum, off);
        float mn = fmaxf(m, mo);
        sum = sum * __expf(m - mn) + so * __expf(mo - mn);
        m = mn;
    }
    float inv = 1.f / sum;

    // accumulate pass; also collect layer-1 stats for free
    float m1 = -1e30f, s1 = 0.f;
    float acc = 0.f;
    for (int base = s; base < tE; base += 64) {
        int j = base + lane;
        unsigned packed = 0;
        if (j < tE) {
            float4 r = eg[j];
            float a = __expf(r.x - m) * inv;
            unsigned ab = (__float_as_uint(a) + 0x8000u) & 0xffff0000u;  // bf16 round
            packed = ab | ((unsigned)__float_as_int(r.z) & 0xffffu);     // src < 2^16
            float ey = r.y;
            float mn = fmaxf(m1, ey);
            s1 = s1 * __expf(m1 - mn) + __expf(ey - mn);
            m1 = mn;
        }
        int cnt = min(64, tE - base);
        for (int k = 0; k < cnt; k++) {
            unsigned pk = __shfl(packed, k);
            float ak = __uint_as_float(pk & 0xffff0000u);
            int sk = (int)(pk & 0xffffu);
            acc += bf2f(lab_bf[(size_t)sk * 64 + lane]) * ak;
        }
    }
    #pragma unroll
    for (int off = 32; off; off >>= 1) {
        float mo = __shfl_xor(m1, off);
        float so = __shfl_xor(s1, off);
        float mn = fmaxf(m1, mo);
        s1 = s1 * __expf(m1 - mn) + so * __expf(mo - mn);
        m1 = mn;
    }
    if (lane == 0) stat1[(size_t)g * NN + v] = make_float2(m1, s1);

    float tm = train_mask[v];
    float res = acc * (1.f - tm) + labels_oh[(size_t)v * 64 + lane] * tm;
    h_buf[(size_t)wid * 64 + lane] = f2bf(res);
}

// ---------------------------------------------------------------------------
// Layer 1 (softmax from precomputed stats) + attention combine + alpha mix
// ---------------------------------------------------------------------------
__global__ __launch_bounds__(256) void final_kernel(
    const ushort* __restrict__ h_buf, const float* __restrict__ labels_oh,
    const float* __restrict__ train_mask, const float* __restrict__ attention,
    const float* __restrict__ alpha, const int* __restrict__ row_start,
    const float4* __restrict__ edges, const float2* __restrict__ stat1,
    const float* __restrict__ out_ns, float* __restrict__ out_logits,
    float* __restrict__ out_lp)
{
    int wid = (blockIdx.x * blockDim.x + threadIdx.x) >> 6;
    int lane = threadIdx.x & 63;
    if (wid >= NN) return;
    int v = wid;
    float tm = train_mask[v];
    float ml = 1.f - tm;
    float moh = labels_oh[(size_t)v * 64 + lane] * tm;
    float a0 = attention[v * 3], a1 = attention[v * 3 + 1], a2 = attention[v * 3 + 2];
    float mx = fmaxf(a0, fmaxf(a1, a2));
    float e0 = __expf(a0 - mx), e1 = __expf(a1 - mx), e2 = __expf(a2 - mx);
    float ainv = 1.f / (e0 + e1 + e2);
    float attw[3] = {e0 * ainv, e1 * ainv, e2 * ainv};
    float lp = 0.f;
    #pragma unroll
    for (int g = 0; g < GG; g++) {
        const int* rs = row_start + (size_t)g * (NN + 1);
        int s = rs[v], tE = rs[v + 1];
        const float4* eg = edges + (size_t)g * EE;
        const ushort* hin = h_buf + (size_t)g * NN * 64;
        float2 st = stat1[(size_t)g * NN + v];
        float m = st.x;
        float inv = 1.f / st.y;

        float acc = 0.f;
        for (int base = s; base < tE; base += 64) {
            int j = base + lane;
            unsigned packed = 0;
            if (j < tE) {
                float4 r = eg[j];
                float a = __expf(r.y - m) * inv;
                unsigned ab = (__float_as_uint(a) + 0x8000u) & 0xffff0000u;
                packed = ab | ((unsigned)__float_as_int(r.z) & 0xffffu);
            }
            int cnt = min(64, tE - base);
            for (int k = 0; k < cnt; k++) {
                unsigned pk = __shfl(packed, k);
                float ak = __uint_as_float(pk & 0xffff0000u);
                int sk = (int)(pk & 0xffffu);
                acc += bf2f(hin[(size_t)sk * 64 + lane]) * ak;
            }
        }
        float hf = acc * ml + moh;
        lp += attw[g] * hf;
    }
    size_t o = (size_t)v * 64 + lane;
    out_lp[o] = lp;
    float al = alpha[v];
    float sg = 1.f / (1.f + __expf(-al));
    out_logits[o] = sg * lp + (1.f - sg) * out_ns[o];
}

// ---------------------------------------------------------------------------
extern "C" void kernel_launch(void* const* d_in, const int* in_sizes, int n_in,
                              void* d_out, int out_size, void* d_ws, size_t ws_size,
                              hipStream_t stream)
{
    const float* features0  = (const float*)d_in[0];
    const float* label_init = (const float*)d_in[1];
    const float* labels_oh  = (const float*)d_in[2];
    const float* train_mask = (const float*)d_in[3];
    const int*   src        = (const int*)d_in[4];
    const int*   dst        = (const int*)d_in[5];
    const float* e_edges    = (const float*)d_in[6];
    const float* attention  = (const float*)d_in[7];
    const float* alpha      = (const float*)d_in[8];
    const float* W1         = (const float*)d_in[9];
    const float* b1         = (const float*)d_in[10];
    const float* W2         = (const float*)d_in[11];
    const float* b2         = (const float*)d_in[12];

    float* out        = (float*)d_out;
    float* out_logits = out;
    float* out_lp     = out + (size_t)NN * CC;
    float* out_ns     = out + 2 * (size_t)NN * CC;

    char* base = (char*)d_ws;
    size_t off = 0;
    auto alloc = [&](size_t bytes) -> void* {
        void* p = base + off;
        off = (off + bytes + 255) & ~(size_t)255;
        return p;
    };
    int*    counts     = (int*)alloc((size_t)GG * NN * sizeof(int));
    int*    row_start  = (int*)alloc((size_t)GG * (NN + 1) * sizeof(int));
    int*    block_sums = (int*)alloc((size_t)GG * NCHUNK * sizeof(int));
    int*    chunk_off  = (int*)alloc((size_t)GG * NCHUNK * sizeof(int));
    float4* edges      = (float4*)alloc((size_t)GG * EE * sizeof(float4));
    ushort* h_buf      = (ushort*)alloc((size_t)GG * NN * CC * sizeof(ushort));
    ushort* lab_bf     = (ushort*)alloc((size_t)NN * CC * sizeof(ushort));
    float2* stat1      = (float2*)alloc((size_t)GG * NN * sizeof(float2));
    // hm (GEMM1 output, 51.2 MB) overlaps the early workspace; the MLP phase
    // completes (stream-ordered) before any CSR array is written -> safe.
    float* hm = (float*)d_ws;

    // ---- MLP: logits_ns = relu(features0 @ W1 + b1) @ W2 + b2 ----
    gemm_kernel<<<dim3((NN + 63) / 64, HH / 64), 256, 0, stream>>>(
        features0, W1, b1, hm, NN, HH, DD, 1);
    gemm_kernel<<<dim3((NN + 63) / 64, CC / 64), 256, 0, stream>>>(
        hm, W2, b2, out_ns, NN, CC, HH, 0);

    // ---- bf16 gather table for label_init (lab_bf is past hm's 51.2 MB) ----
    cvt_kernel<<<(NN * CC / 4 + 255) / 256, 256, 0, stream>>>(
        label_init, lab_bf, NN * CC / 4);

    // ---- CSR build ----
    hipMemsetAsync(counts, 0, (size_t)GG * NN * sizeof(int), stream);
    hist_kernel<<<(GG * EE + 255) / 256, 256, 0, stream>>>(dst, counts);
    scan_phase1<<<GG * NCHUNK, 256, 0, stream>>>(counts, row_start, block_sums);
    scan_phase2<<<GG, 256, 0, stream>>>(block_sums, chunk_off, row_start);
    scan_phase3<<<GG * NCHUNK, 256, 0, stream>>>(row_start, chunk_off);
    hipMemsetAsync(counts, 0, (size_t)GG * NN * sizeof(int), stream);  // reuse as fill
    scatter_kernel<<<(GG * EE + 255) / 256, 256, 0, stream>>>(
        dst, src, e_edges, row_start, counts, edges);

    // ---- Layer 0 propagation (fused softmax + L1 stats) ----
    prop0_kernel<<<((size_t)GG * NN * 64 + 255) / 256, 256, 0, stream>>>(
        lab_bf, labels_oh, train_mask, row_start, edges, h_buf, stat1);

    // ---- Layer 1 + attention combine + alpha mix ----
    final_kernel<<<((size_t)NN * 64 + 255) / 256, 256, 0, stream>>>(
        h_buf, labels_oh, train_mask, attention, alpha, row_start, edges,
        stat1, out_ns, out_logits, out_lp);
}

// Round 5
// 821.661 us; speedup vs baseline: 2.1107x; 1.2732x over previous
//
#include <hip/hip_runtime.h>
#include <hip/hip_bf16.h>

#define NN 50000
#define CC 64
#define GG 3
#define EE 1200000
#define LL 2
#define DD 256
#define HH 256
#define NCHUNK 196   // ceil(NN/256)

// Edge record, CSR-ordered: float4 = {e0 logit, e1 logit, src (int bits), pad}.
// One 16B random write at build; read-only afterwards.
// Gather tables (label_init, h_buf) are bf16 (ushort): 128B rows.

__device__ __forceinline__ ushort f2bf(float f) {
    unsigned b = __float_as_uint(f);
    return (ushort)((b + 0x7fffu + ((b >> 16) & 1u)) >> 16);
}
__device__ __forceinline__ float bf2f(ushort u) {
    return __uint_as_float(((unsigned)u) << 16);
}

// ---------------------------------------------------------------------------
// GEMM: C[M,Nc] = act(A[M,K] @ B[K,Nc] + bias), fp32, 64x64 tile, 4x4 micro
// ---------------------------------------------------------------------------
__global__ __launch_bounds__(256) void gemm_kernel(
    const float* __restrict__ A, const float* __restrict__ B,
    const float* __restrict__ bias, float* __restrict__ Cout,
    int M, int Nc, int K, int do_relu)
{
    __shared__ float As[16][68];
    __shared__ float Bs[16][64];
    int tid = threadIdx.x;
    int tx = tid & 15;
    int ty = tid >> 4;
    int m0 = blockIdx.x * 64;
    int n0 = blockIdx.y * 64;
    float acc[4][4] = {};

    for (int k0 = 0; k0 < K; k0 += 16) {
        {
            int kk = tid & 15;
            int mm = tid >> 4;
            #pragma unroll
            for (int i = 0; i < 4; i++) {
                int m = m0 + mm + i * 16;
                float v = (m < M) ? A[(size_t)m * K + k0 + kk] : 0.f;
                As[kk][mm + i * 16] = v;
            }
        }
        {
            int nn = tid & 63;
            int kk = tid >> 6;
            #pragma unroll
            for (int i = 0; i < 4; i++) {
                Bs[kk + i * 4][nn] = B[(size_t)(k0 + kk + i * 4) * Nc + n0 + nn];
            }
        }
        __syncthreads();
        #pragma unroll
        for (int kk = 0; kk < 16; kk++) {
            float4 a4 = *(const float4*)&As[kk][ty * 4];
            float4 b4 = *(const float4*)&Bs[kk][tx * 4];
            acc[0][0] += a4.x * b4.x; acc[0][1] += a4.x * b4.y;
            acc[0][2] += a4.x * b4.z; acc[0][3] += a4.x * b4.w;
            acc[1][0] += a4.y * b4.x; acc[1][1] += a4.y * b4.y;
            acc[1][2] += a4.y * b4.z; acc[1][3] += a4.y * b4.w;
            acc[2][0] += a4.z * b4.x; acc[2][1] += a4.z * b4.y;
            acc[2][2] += a4.z * b4.z; acc[2][3] += a4.z * b4.w;
            acc[3][0] += a4.w * b4.x; acc[3][1] += a4.w * b4.y;
            acc[3][2] += a4.w * b4.z; acc[3][3] += a4.w * b4.w;
        }
        __syncthreads();
    }
    #pragma unroll
    for (int i = 0; i < 4; i++) {
        int m = m0 + ty * 4 + i;
        if (m >= M) continue;
        #pragma unroll
        for (int j = 0; j < 4; j++) {
            int n = n0 + tx * 4 + j;
            float v = acc[i][j] + bias[n];
            if (do_relu) v = fmaxf(v, 0.f);
            Cout[(size_t)m * Nc + n] = v;
        }
    }
}

// ---------------------------------------------------------------------------
// fp32 -> bf16 table conversion (vectorized 4-wide)
// ---------------------------------------------------------------------------
__global__ void cvt_kernel(const float* __restrict__ in, ushort* __restrict__ out, int n4)
{
    int i = blockIdx.x * blockDim.x + threadIdx.x;
    if (i >= n4) return;
    float4 f = ((const float4*)in)[i];
    ushort4 u;
    u.x = f2bf(f.x); u.y = f2bf(f.y); u.z = f2bf(f.z); u.w = f2bf(f.w);
    ((ushort4*)out)[i] = u;
}

// ---------------------------------------------------------------------------
// CSR build
// ---------------------------------------------------------------------------
__global__ void hist_kernel(const int* __restrict__ dst, int* __restrict__ counts)
{
    int idx = blockIdx.x * blockDim.x + threadIdx.x;
    if (idx >= GG * EE) return;
    int g = idx / EE;
    atomicAdd(&counts[g * NN + dst[idx]], 1);
}

__global__ void scan_phase1(const int* __restrict__ counts, int* __restrict__ rs,
                            int* __restrict__ block_sums)
{
    int b = blockIdx.x;
    int g = b / NCHUNK;
    int c = b - g * NCHUNK;
    int t = threadIdx.x;
    int i = c * 256 + t;
    __shared__ int sd[256];
    int v = (i < NN) ? counts[(size_t)g * NN + i] : 0;
    sd[t] = v;
    __syncthreads();
    for (int off = 1; off < 256; off <<= 1) {
        int x = (t >= off) ? sd[t - off] : 0;
        __syncthreads();
        sd[t] += x;
        __syncthreads();
    }
    if (i < NN) rs[(size_t)g * (NN + 1) + i] = sd[t] - v;
    if (t == 255) block_sums[b] = sd[255];
}

__global__ void scan_phase2(const int* __restrict__ block_sums,
                            int* __restrict__ chunk_off, int* __restrict__ rs)
{
    int g = blockIdx.x;
    int t = threadIdx.x;
    __shared__ int sd[256];
    int v = (t < NCHUNK) ? block_sums[g * NCHUNK + t] : 0;
    sd[t] = v;
    __syncthreads();
    for (int off = 1; off < 256; off <<= 1) {
        int x = (t >= off) ? sd[t - off] : 0;
        __syncthreads();
        sd[t] += x;
        __syncthreads();
    }
    if (t < NCHUNK) chunk_off[g * NCHUNK + t] = sd[t] - v;
    if (t == 255) rs[(size_t)g * (NN + 1) + NN] = sd[255];
}

__global__ void scan_phase3(int* __restrict__ rs, const int* __restrict__ chunk_off)
{
    int b = blockIdx.x;
    int g = b / NCHUNK;
    int c = b - g * NCHUNK;
    int i = c * 256 + threadIdx.x;
    if (i < NN) rs[(size_t)g * (NN + 1) + i] += chunk_off[g * NCHUNK + c];
}

__global__ void scatter_kernel(const int* __restrict__ dst, const int* __restrict__ src,
                               const float* __restrict__ e_edges,
                               const int* __restrict__ row_start, int* __restrict__ fill,
                               float4* __restrict__ edges)
{
    int idx = blockIdx.x * blockDim.x + threadIdx.x;
    if (idx >= GG * EE) return;
    int g = idx / EE;
    int e = idx - g * EE;
    int d = dst[idx];
    int p = atomicAdd(&fill[g * NN + d], 1) + row_start[(size_t)g * (NN + 1) + d];
    float4 rec;
    rec.x = e_edges[(size_t)g * EE + e];
    rec.y = e_edges[(size_t)(GG + g) * EE + e];
    rec.z = __int_as_float(src[idx]);
    rec.w = 0.f;
    edges[(size_t)g * EE + p] = rec;
}

// ---------------------------------------------------------------------------
// Batched gather-accumulate: 8 independent loads in flight per wave.
// Out-of-range k self-masks: lanes past tE carry packed=0 (weight +0, row 0).
// ---------------------------------------------------------------------------
__device__ __forceinline__ void consume8(unsigned packed, int cnt,
                                         const ushort* __restrict__ tab,
                                         int lane, float& acc)
{
    for (int k0 = 0; k0 < cnt; k0 += 8) {
        unsigned pk[8];
        #pragma unroll
        for (int u = 0; u < 8; u++) pk[u] = __shfl(packed, k0 + u);
        float vals[8];
        #pragma unroll
        for (int u = 0; u < 8; u++)
            vals[u] = bf2f(tab[(size_t)(pk[u] & 0xffffu) * 64 + lane]);
        #pragma unroll
        for (int u = 0; u < 8; u++)
            acc = fmaf(vals[u], __uint_as_float(pk[u] & 0xffff0000u), acc);
    }
}

// ---------------------------------------------------------------------------
// Layer 0 propagation + fused L0 softmax + L1 softmax stats: wave per (g,node)
// ---------------------------------------------------------------------------
__global__ __launch_bounds__(256) void prop0_kernel(
    const ushort* __restrict__ lab_bf, const float* __restrict__ labels_oh,
    const float* __restrict__ train_mask, const int* __restrict__ row_start,
    const float4* __restrict__ edges, ushort* __restrict__ h_buf,
    float2* __restrict__ stat1)
{
    int wid = (blockIdx.x * blockDim.x + threadIdx.x) >> 6;
    int lane = threadIdx.x & 63;
    if (wid >= GG * NN) return;
    int g = wid / NN;
    int v = wid - g * NN;
    const int* rs = row_start + (size_t)g * (NN + 1);
    int s = rs[v], tE = rs[v + 1];
    const float4* eg = edges + (size_t)g * EE;

    // layer-0 softmax stats (lane-strided online, then butterfly)
    float m = -1e30f, sum = 0.f;
    for (int j = s + lane; j < tE; j += 64) {
        float e0 = eg[j].x;
        float mn = fmaxf(m, e0);
        sum = sum * __expf(m - mn) + __expf(e0 - mn);
        m = mn;
    }
    #pragma unroll
    for (int off = 32; off; off >>= 1) {
        float mo = __shfl_xor(m, off);
        float so = __shfl_xor(sum, off);
        float mn = fmaxf(m, mo);
        sum = sum * __expf(m - mn) + so * __expf(mo - mn);
        m = mn;
    }
    float inv = 1.f / sum;

    // accumulate pass; also collect layer-1 stats for free
    float m1 = -1e30f, s1 = 0.f;
    float acc = 0.f;
    for (int base = s; base < tE; base += 64) {
        int j = base + lane;
        unsigned packed = 0;
        if (j < tE) {
            float4 r = eg[j];
            float a = __expf(r.x - m) * inv;
            unsigned ab = (__float_as_uint(a) + 0x8000u) & 0xffff0000u;  // bf16 round
            packed = ab | ((unsigned)__float_as_int(r.z) & 0xffffu);     // src < 2^16
            float ey = r.y;
            float mn = fmaxf(m1, ey);
            s1 = s1 * __expf(m1 - mn) + __expf(ey - mn);
            m1 = mn;
        }
        int cnt = min(64, tE - base);
        consume8(packed, cnt, lab_bf, lane, acc);
    }
    #pragma unroll
    for (int off = 32; off; off >>= 1) {
        float mo = __shfl_xor(m1, off);
        float so = __shfl_xor(s1, off);
        float mn = fmaxf(m1, mo);
        s1 = s1 * __expf(m1 - mn) + so * __expf(mo - mn);
        m1 = mn;
    }
    if (lane == 0) stat1[(size_t)g * NN + v] = make_float2(m1, s1);

    float tm = train_mask[v];
    float res = acc * (1.f - tm) + labels_oh[(size_t)v * 64 + lane] * tm;
    h_buf[(size_t)wid * 64 + lane] = f2bf(res);
}

// ---------------------------------------------------------------------------
// Layer 1 (softmax from precomputed stats) + attention combine + alpha mix
// ---------------------------------------------------------------------------
__global__ __launch_bounds__(256) void final_kernel(
    const ushort* __restrict__ h_buf, const float* __restrict__ labels_oh,
    const float* __restrict__ train_mask, const float* __restrict__ attention,
    const float* __restrict__ alpha, const int* __restrict__ row_start,
    const float4* __restrict__ edges, const float2* __restrict__ stat1,
    const float* __restrict__ out_ns, float* __restrict__ out_logits,
    float* __restrict__ out_lp)
{
    int wid = (blockIdx.x * blockDim.x + threadIdx.x) >> 6;
    int lane = threadIdx.x & 63;
    if (wid >= NN) return;
    int v = wid;
    float tm = train_mask[v];
    float ml = 1.f - tm;
    float moh = labels_oh[(size_t)v * 64 + lane] * tm;
    float a0 = attention[v * 3], a1 = attention[v * 3 + 1], a2 = attention[v * 3 + 2];
    float mx = fmaxf(a0, fmaxf(a1, a2));
    float e0 = __expf(a0 - mx), e1 = __expf(a1 - mx), e2 = __expf(a2 - mx);
    float ainv = 1.f / (e0 + e1 + e2);
    float attw[3] = {e0 * ainv, e1 * ainv, e2 * ainv};
    float lp = 0.f;
    #pragma unroll
    for (int g = 0; g < GG; g++) {
        const int* rs = row_start + (size_t)g * (NN + 1);
        int s = rs[v], tE = rs[v + 1];
        const float4* eg = edges + (size_t)g * EE;
        const ushort* hin = h_buf + (size_t)g * NN * 64;
        float2 st = stat1[(size_t)g * NN + v];
        float m = st.x;
        float inv = 1.f / st.y;

        float acc = 0.f;
        for (int base = s; base < tE; base += 64) {
            int j = base + lane;
            unsigned packed = 0;
            if (j < tE) {
                float4 r = eg[j];
                float a = __expf(r.y - m) * inv;
                unsigned ab = (__float_as_uint(a) + 0x8000u) & 0xffff0000u;
                packed = ab | ((unsigned)__float_as_int(r.z) & 0xffffu);
            }
            int cnt = min(64, tE - base);
            consume8(packed, cnt, hin, lane, acc);
        }
        float hf = acc * ml + moh;
        lp += attw[g] * hf;
    }
    size_t o = (size_t)v * 64 + lane;
    out_lp[o] = lp;
    float al = alpha[v];
    float sg = 1.f / (1.f + __expf(-al));
    out_logits[o] = sg * lp + (1.f - sg) * out_ns[o];
}

// ---------------------------------------------------------------------------
extern "C" void kernel_launch(void* const* d_in, const int* in_sizes, int n_in,
                              void* d_out, int out_size, void* d_ws, size_t ws_size,
                              hipStream_t stream)
{
    const float* features0  = (const float*)d_in[0];
    const float* label_init = (const float*)d_in[1];
    const float* labels_oh  = (const float*)d_in[2];
    const float* train_mask = (const float*)d_in[3];
    const int*   src        = (const int*)d_in[4];
    const int*   dst        = (const int*)d_in[5];
    const float* e_edges    = (const float*)d_in[6];
    const float* attention  = (const float*)d_in[7];
    const float* alpha      = (const float*)d_in[8];
    const float* W1         = (const float*)d_in[9];
    const float* b1         = (const float*)d_in[10];
    const float* W2         = (const float*)d_in[11];
    const float* b2         = (const float*)d_in[12];

    float* out        = (float*)d_out;
    float* out_logits = out;
    float* out_lp     = out + (size_t)NN * CC;
    float* out_ns     = out + 2 * (size_t)NN * CC;

    char* base = (char*)d_ws;
    size_t off = 0;
    auto alloc = [&](size_t bytes) -> void* {
        void* p = base + off;
        off = (off + bytes + 255) & ~(size_t)255;
        return p;
    };
    int*    counts     = (int*)alloc((size_t)GG * NN * sizeof(int));
    int*    row_start  = (int*)alloc((size_t)GG * (NN + 1) * sizeof(int));
    int*    block_sums = (int*)alloc((size_t)GG * NCHUNK * sizeof(int));
    int*    chunk_off  = (int*)alloc((size_t)GG * NCHUNK * sizeof(int));
    float4* edges      = (float4*)alloc((size_t)GG * EE * sizeof(float4));
    ushort* h_buf      = (ushort*)alloc((size_t)GG * NN * CC * sizeof(ushort));
    ushort* lab_bf     = (ushort*)alloc((size_t)NN * CC * sizeof(ushort));
    float2* stat1      = (float2*)alloc((size_t)GG * NN * sizeof(float2));
    // hm (GEMM1 output, 51.2 MB) overlaps the early workspace; the MLP phase
    // completes (stream-ordered) before any CSR array is written -> safe.
    float* hm = (float*)d_ws;

    // ---- MLP: logits_ns = relu(features0 @ W1 + b1) @ W2 + b2 ----
    gemm_kernel<<<dim3((NN + 63) / 64, HH / 64), 256, 0, stream>>>(
        features0, W1, b1, hm, NN, HH, DD, 1);
    gemm_kernel<<<dim3((NN + 63) / 64, CC / 64), 256, 0, stream>>>(
        hm, W2, b2, out_ns, NN, CC, HH, 0);

    // ---- bf16 gather table for label_init (lab_bf is past hm's 51.2 MB) ----
    cvt_kernel<<<(NN * CC / 4 + 255) / 256, 256, 0, stream>>>(
        label_init, lab_bf, NN * CC / 4);

    // ---- CSR build ----
    hipMemsetAsync(counts, 0, (size_t)GG * NN * sizeof(int), stream);
    hist_kernel<<<(GG * EE + 255) / 256, 256, 0, stream>>>(dst, counts);
    scan_phase1<<<GG * NCHUNK, 256, 0, stream>>>(counts, row_start, block_sums);
    scan_phase2<<<GG, 256, 0, stream>>>(block_sums, chunk_off, row_start);
    scan_phase3<<<GG * NCHUNK, 256, 0, stream>>>(row_start, chunk_off);
    hipMemsetAsync(counts, 0, (size_t)GG * NN * sizeof(int), stream);  // reuse as fill
    scatter_kernel<<<(GG * EE + 255) / 256, 256, 0, stream>>>(
        dst, src, e_edges, row_start, counts, edges);

    // ---- Layer 0 propagation (fused softmax + L1 stats) ----
    prop0_kernel<<<((size_t)GG * NN * 64 + 255) / 256, 256, 0, stream>>>(
        lab_bf, labels_oh, train_mask, row_start, edges, h_buf, stat1);

    // ---- Layer 1 + attention combine + alpha mix ----
    final_kernel<<<((size_t)NN * 64 + 255) / 256, 256, 0, stream>>>(
        h_buf, labels_oh, train_mask, attention, alpha, row_start, edges,
        stat1, out_ns, out_logits, out_lp);
}